// Round 2
// baseline (329.243 us; speedup 1.0000x reference)
//
#include <hip/hip_runtime.h>
#include <hip/hip_bf16.h>
#include <stdint.h>

#define B_SZ 4
#define C_IN 256
#define N_SP 4096
#define HEADS 4
#define DH 32
#define HID 128

#define BI 64       // queries per block (4 waves x 16)
#define BJ 64       // keys per iteration
#define PP 68       // P LDS row pitch in shorts (136 B, 8B-aligned, ~2-way banks)

typedef short short4v __attribute__((ext_vector_type(4)));
typedef short short8 __attribute__((ext_vector_type(8)));
typedef float f32x4 __attribute__((ext_vector_type(4)));

#if __has_builtin(__builtin_amdgcn_exp2f)
#define EXP2 __builtin_amdgcn_exp2f
#else
#define EXP2 exp2f
#endif

__device__ __forceinline__ short f2bfs(float f) {  // round-half-up f32->bf16
  return (short)((__float_as_uint(f) + 0x8000u) >> 16);
}
__device__ __forceinline__ float bfs2f(short s) {  // bf16->f32
  return __uint_as_float(((uint32_t)(unsigned short)s) << 16);
}
__device__ __forceinline__ short8 ld_frag(const short* p) {  // 8B-aligned 16B LDS read
  short4v a = *(const short4v*)p;
  short4v b = *(const short4v*)(p + 4);
  return __builtin_shufflevector(a, b, 0, 1, 2, 3, 4, 5, 6, 7);
}
__device__ __forceinline__ f32x4 mfma16(short8 a, short8 b, f32x4 c) {
  return __builtin_amdgcn_mfma_f32_16x16x32_bf16(a, b, c, 0, 0, 0);
}

// ---------------- Kernel 0: prep — transpose+split x -> bf16 hi/lo [b][n][c];
// convert w_qkv / w_out -> bf16 hi/lo ([o][c], k-contiguous).
// Re-gridded: one 64n x 64c chunk per block (1024 x-blocks = 4/CU).
__global__ __launch_bounds__(256) void prep_k(
    const float* __restrict__ x, const float* __restrict__ w_qkv,
    const float* __restrict__ w_out,
    short* __restrict__ xh, short* __restrict__ xl,
    short* __restrict__ wqh, short* __restrict__ wql,
    short* __restrict__ woh, short* __restrict__ wol) {
  const int t = threadIdx.x;
  const int bx = blockIdx.x;
  if (bx < 1024) {  // x transpose blocks: 64 n x 64 c per block
    __shared__ float T[64 * 65];  // [n][c-chunk], pitch 65 (2-way banks = free)
    const int b = bx >> 8, n0 = ((bx >> 2) & 63) * 64, c0 = (bx & 3) * 64;
    const float* xb = x + (size_t)b * C_IN * N_SP;
    {  // read 64c x 64n coalesced (wave reads 64 consecutive n at fixed c)
      const int n = t & 63, cw = t >> 6;
#pragma unroll
      for (int i = 0; i < 16; ++i) {
        const int c = cw * 16 + i;
        T[n * 65 + c] = xb[(size_t)(c0 + c) * N_SP + n0 + n];
      }
    }
    __syncthreads();
    {  // write hi/lo rows [n][c]: 16B stores, 4 lanes cover 32B/row
      const int n = t >> 2, cg = t & 3;
#pragma unroll
      for (int j = 0; j < 2; ++j) {
        const int c = cg * 16 + j * 8;
        short8 hv, lv;
#pragma unroll
        for (int e = 0; e < 8; ++e) {
          const float v = T[n * 65 + c + e];
          const short hh = f2bfs(v);
          hv[e] = hh;
          lv[e] = f2bfs(v - bfs2f(hh));
        }
        const size_t off = ((size_t)(b * N_SP + n0 + n)) * C_IN + c0 + c;
        *(short8*)(xh + off) = hv;
        *(short8*)(xl + off) = lv;
      }
    }
  } else {  // weight blocks: flat convert 131072 floats
    const int f0 = (bx - 1024) * 8192;
#pragma unroll
    for (int j = 0; j < 32; ++j) {
      const int f = f0 + j * 256 + t;
      float v;
      short *dh, *dl;
      int idx;
      if (f < 384 * 256) { v = w_qkv[f]; dh = wqh; dl = wql; idx = f; }
      else { idx = f - 384 * 256; v = w_out[idx]; dh = woh; dl = wol; }
      const short hh = f2bfs(v);
      dh[idx] = hh;
      dl[idx] = f2bfs(v - bfs2f(hh));
    }
  }
}

// ---------------- Kernel 1: QKV projection, bf16x3 MFMA ----------------
// grid (64 ntiles, 3 osec, 4 b); wave = 16 n, 128 o (8 o-tiles).
// osec 0/1 (q/k): D[o][n] -> qt/kt [bh][n][d] (scale*log2e folded into q).
// osec 2 (v): swapped operands -> D[n][o] -> vt [bh][d][n].
__global__ __launch_bounds__(256) void qkv_mfma_k(
    const short* __restrict__ xh, const short* __restrict__ xl,
    const short* __restrict__ wqh, const short* __restrict__ wql,
    short* __restrict__ qt, short* __restrict__ kt, short* __restrict__ vt) {
  const int t = threadIdx.x;
  const int lane = t & 63, w = t >> 6;
  const int l15 = lane & 15, quad = lane >> 4;
  const int osec = blockIdx.y, b = blockIdx.z;
  const int n0 = blockIdx.x * 64 + w * 16;
  const size_t xrow = ((size_t)(b * N_SP + n0 + l15)) * C_IN;
  const size_t wrow = ((size_t)(osec * 128 + l15)) * C_IN;
  const bool isv = (osec == 2);
  const f32x4 zz = {0.f, 0.f, 0.f, 0.f};
  f32x4 acc[8];
#pragma unroll
  for (int ot = 0; ot < 8; ++ot) acc[ot] = zz;

  for (int k0 = 0; k0 < C_IN; k0 += 32) {
    const int ko = k0 + quad * 8;
    const short8 xhf = *(const short8*)(xh + xrow + ko);
    const short8 xlf = *(const short8*)(xl + xrow + ko);
#pragma unroll
    for (int ot = 0; ot < 8; ++ot) {
      const size_t wo = wrow + (size_t)ot * 16 * C_IN + ko;
      const short8 whf = *(const short8*)(wqh + wo);
      const short8 wlf = *(const short8*)(wql + wo);
      if (isv) {  // A = x (rows n), B = w (rows o)
        acc[ot] = mfma16(xhf, whf, acc[ot]);
        acc[ot] = mfma16(xlf, whf, acc[ot]);
        acc[ot] = mfma16(xhf, wlf, acc[ot]);
      } else {    // A = w (rows o), B = x (rows n)
        acc[ot] = mfma16(whf, xhf, acc[ot]);
        acc[ot] = mfma16(whf, xlf, acc[ot]);
        acc[ot] = mfma16(wlf, xhf, acc[ot]);
      }
    }
  }

  if (!isv) {  // lane holds o = osec*128 + ot*16 + quad*4 + r, n = n0 + l15
    const float sc = osec ? 1.f : (0.17677669529663687f * 1.4426950408889634f);
    short* dst = osec ? kt : qt;
    const int n = n0 + l15;
#pragma unroll
    for (int ot = 0; ot < 8; ++ot) {
      const int ol = ot * 16 + quad * 4;
      const int h = ol >> 5, d0 = ol & 31;
      short4v p;
#pragma unroll
      for (int r = 0; r < 4; ++r) p[r] = f2bfs(acc[ot][r] * sc);
      *(short4v*)(dst + ((size_t)(b * HEADS + h) * N_SP + n) * DH + d0) = p;
    }
  } else {     // lane holds n = n0 + quad*4 + r, o = 256 + ot*16 + l15
    const int n = n0 + quad * 4;
#pragma unroll
    for (int ot = 0; ot < 8; ++ot) {
      const int ol = ot * 16 + l15;
      const int h = ol >> 5, d = ol & 31;
      short4v p;
#pragma unroll
      for (int r = 0; r < 4; ++r) p[r] = f2bfs(acc[ot][r]);
      *(short4v*)(vt + ((size_t)(b * HEADS + h) * DH + d) * N_SP + n) = p;
    }
  }
}

// ---------------- Kernel 2: flash attention, bf16 MFMA ----------------
// BI=64: grid 64x16 = 1024 blocks = 4/CU (occupancy fix). Wave owns 16 i rows.
// cvt_pk P-pack + setprio around MFMA clusters.
__global__ __launch_bounds__(256, 4) void attn_k(
    const short* __restrict__ qt, const short* __restrict__ kt,
    const short* __restrict__ vt, short* __restrict__ ath,
    short* __restrict__ atl) {
  __shared__ short Ps[BI * PP];    // 8704 B, [i][j] bf16, rows owned per-wave
  __shared__ float Osh[DH * 68];   // 8704 B, epilogue transpose
  const int t = threadIdx.x;
  const int lane = t & 63, w = t >> 6;
  const int l15 = lane & 15, quad = lane >> 4;
  const int i0 = blockIdx.x * BI;
  const int bh = blockIdx.y;
  const short* qg = qt + ((size_t)bh * N_SP + i0) * DH;
  const short* kg = kt + (size_t)bh * N_SP * DH;
  const short* vg = vt + (size_t)bh * DH * N_SP;

  // Q fragment (loop-invariant): B[n=i][k=d]
  const short8 bq = *(const short8*)(qg + (size_t)(w * 16 + l15) * DH + quad * 8);

  const f32x4 zz = {0.f, 0.f, 0.f, 0.f};
  f32x4 o_acc[2] = {zz, zz};  // [dt]
  float lsum = 0.f;
  short* prow = Ps + (w * 16 + l15) * PP;

  short8 akA[4], akB[4], vbA[2][2], vbB[2][2];
#pragma unroll
  for (int jt = 0; jt < 4; ++jt)
    akA[jt] = *(const short8*)(kg + (size_t)(jt * 16 + l15) * DH + quad * 8);
#pragma unroll
  for (int dt = 0; dt < 2; ++dt)
#pragma unroll
    for (int kk = 0; kk < 2; ++kk)
      vbA[dt][kk] = *(const short8*)(vg + (size_t)(dt * 16 + l15) * N_SP + kk * 32 + quad * 8);

  auto body = [&](const short8 (&akc)[4], const short8 (&vbc)[2][2],
                  short8 (&akn)[4], short8 (&vbn)[2][2], int jn) {
    // S^T tiles: D[j][i] = mfma(K, Q)
    f32x4 sf[4];
    __builtin_amdgcn_s_setprio(1);
#pragma unroll
    for (int jt = 0; jt < 4; ++jt) sf[jt] = mfma16(akc[jt], bq, zz);
    __builtin_amdgcn_s_setprio(0);
    // prefetch next tile's K/V into the alternate register set
#pragma unroll
    for (int jt = 0; jt < 4; ++jt)
      akn[jt] = *(const short8*)(kg + (size_t)(jn + jt * 16 + l15) * DH + quad * 8);
#pragma unroll
    for (int dt = 0; dt < 2; ++dt)
#pragma unroll
      for (int kk = 0; kk < 2; ++kk)
        vbn[dt][kk] = *(const short8*)(vg + (size_t)(dt * 16 + l15) * N_SP + jn + kk * 32 + quad * 8);
    // exp2 (no max), accumulate l, pack P[i][j] via v_cvt_pk_bf16_f32
#pragma unroll
    for (int jt = 0; jt < 4; ++jt) {
      const float e0 = EXP2(sf[jt][0]);
      const float e1 = EXP2(sf[jt][1]);
      const float e2 = EXP2(sf[jt][2]);
      const float e3 = EXP2(sf[jt][3]);
      lsum += (e0 + e1) + (e2 + e3);
      uint2 pk;
      asm("v_cvt_pk_bf16_f32 %0, %1, %2" : "=v"(pk.x) : "v"(e0), "v"(e1));
      asm("v_cvt_pk_bf16_f32 %0, %1, %2" : "=v"(pk.y) : "v"(e2), "v"(e3));
      *(uint2*)(prow + jt * 16 + quad * 4) = pk;
    }
    asm volatile("s_waitcnt lgkmcnt(0)" ::: "memory");  // same-wave P write->read
    // O += P V^T
    short8 pa[2];
#pragma unroll
    for (int kk = 0; kk < 2; ++kk) pa[kk] = ld_frag(prow + kk * 32 + quad * 8);
    __builtin_amdgcn_s_setprio(1);
#pragma unroll
    for (int dt = 0; dt < 2; ++dt) {
      o_acc[dt] = mfma16(pa[0], vbc[dt][0], o_acc[dt]);
      o_acc[dt] = mfma16(pa[1], vbc[dt][1], o_acc[dt]);
    }
    __builtin_amdgcn_s_setprio(0);
  };

  for (int jt0 = 0; jt0 < N_SP; jt0 += 2 * BJ) {
    body(akA, vbA, akB, vbB, (jt0 + BJ) & (N_SP - 1));
    body(akB, vbB, akA, vbA, (jt0 + 2 * BJ) & (N_SP - 1));
  }

  // finalize l: reduce over quads (lanes sharing l15)
  lsum += __shfl_xor(lsum, 16);
  lsum += __shfl_xor(lsum, 32);
  float linv[4];
#pragma unroll
  for (int r = 0; r < 4; ++r) linv[r] = 1.f / __shfl(lsum, quad * 4 + r);
  // normalize + transpose to Osh[d][i]
#pragma unroll
  for (int dt = 0; dt < 2; ++dt)
#pragma unroll
    for (int r = 0; r < 4; ++r)
      Osh[(dt * 16 + l15) * 68 + w * 16 + quad * 4 + r] = o_acc[dt][r] * linv[r];
  __syncthreads();
  {  // emit att bf16 hi/lo in [b][n][hid]: thread owns (row ii, 8-d chunk)
    const int ii = t & 63, half = t >> 6;
    const int b = bh >> 2, h = bh & 3;
    short8 hv, lv;
#pragma unroll
    for (int e = 0; e < 8; ++e) {
      const int d = half * 8 + e;
      const float v = Osh[d * 68 + ii];
      const short hh = f2bfs(v);
      hv[e] = hh;
      lv[e] = f2bfs(v - bfs2f(hh));
    }
    const size_t off = ((size_t)(b * N_SP + i0 + ii)) * HID + h * 32 + half * 8;
    *(short8*)(ath + off) = hv;
    *(short8*)(atl + off) = lv;
  }
}

// ---------------- Kernel 3: output projection + bias, bf16x3 MFMA ----------------
// grid (64 ntiles, 2 osec, 4 b); wave = 16 n, 128 o. Swapped operands:
// A = att (rows n), B = w_out (rows o) -> lane holds 4 consecutive n -> float4 store.
__global__ __launch_bounds__(256) void out_mfma_k(
    const short* __restrict__ ath, const short* __restrict__ atl,
    const short* __restrict__ woh, const short* __restrict__ wol,
    const float* __restrict__ bias, float* __restrict__ out) {
  const int t = threadIdx.x;
  const int lane = t & 63, w = t >> 6;
  const int l15 = lane & 15, quad = lane >> 4;
  const int osec = blockIdx.y, b = blockIdx.z;
  const int n0 = blockIdx.x * 64 + w * 16;
  const size_t arow = ((size_t)(b * N_SP + n0 + l15)) * HID;
  const size_t wrow = ((size_t)(osec * 128 + l15)) * HID;
  const f32x4 zz = {0.f, 0.f, 0.f, 0.f};
  f32x4 acc[8];
#pragma unroll
  for (int ot = 0; ot < 8; ++ot) acc[ot] = zz;

  for (int k0 = 0; k0 < HID; k0 += 32) {
    const int ko = k0 + quad * 8;
    const short8 ahf = *(const short8*)(ath + arow + ko);
    const short8 alf = *(const short8*)(atl + arow + ko);
#pragma unroll
    for (int ot = 0; ot < 8; ++ot) {
      const size_t wo = wrow + (size_t)ot * 16 * HID + ko;
      const short8 whf = *(const short8*)(woh + wo);
      const short8 wlf = *(const short8*)(wol + wo);
      acc[ot] = mfma16(ahf, whf, acc[ot]);
      acc[ot] = mfma16(alf, whf, acc[ot]);
      acc[ot] = mfma16(ahf, wlf, acc[ot]);
    }
  }
  // lane holds n = n0 + quad*4 + r, o = osec*128 + ot*16 + l15
#pragma unroll
  for (int ot = 0; ot < 8; ++ot) {
    const int o = osec * 128 + ot * 16 + l15;
    const float bv = bias[o];
    float4 v = make_float4(acc[ot][0] + bv, acc[ot][1] + bv,
                           acc[ot][2] + bv, acc[ot][3] + bv);
    *(float4*)(out + ((size_t)(b * C_IN + o)) * N_SP + n0 + quad * 4) = v;
  }
}

extern "C" void kernel_launch(void* const* d_in, const int* in_sizes, int n_in,
                              void* d_out, int out_size, void* d_ws, size_t ws_size,
                              hipStream_t stream) {
  const float* x = (const float*)d_in[0];
  const float* w_qkv = (const float*)d_in[1];
  const float* w_out = (const float*)d_in[2];
  const float* b_out = (const float*)d_in[3];
  float* out = (float*)d_out;

  // workspace layout (bf16 shorts), ~28.5 MiB total:
  short* xh = (short*)d_ws;                         // 4*4096*256 = 8.39 MB
  short* xl = xh + (size_t)B_SZ * N_SP * C_IN;      // 8.39 MB
  short* wqh = xl + (size_t)B_SZ * N_SP * C_IN;     // 384*256*2B
  short* wql = wqh + 384 * C_IN;
  short* woh = wql + 384 * C_IN;                    // 256*128*2B
  short* wol = woh + C_IN * HID;
  short* qt = wol + C_IN * HID;                     // 16*4096*32 = 4 MB
  short* kt = qt + (size_t)16 * N_SP * DH;          // 4 MB
  short* vt = kt + (size_t)16 * N_SP * DH;          // 4 MB
  short* ath = xh;                                  // alias: xh/xl dead after qkv_mfma
  short* atl = ath + (size_t)B_SZ * N_SP * HID;     // both fit exactly in xh region

  prep_k<<<dim3(1040), 256, 0, stream>>>(x, w_qkv, w_out, xh, xl, wqh, wql, woh, wol);
  qkv_mfma_k<<<dim3(64, 3, B_SZ), 256, 0, stream>>>(xh, xl, wqh, wql, qt, kt, vt);
  attn_k<<<dim3(N_SP / BI, B_SZ * HEADS), 256, 0, stream>>>(qt, kt, vt, ath, atl);
  out_mfma_k<<<dim3(64, 2, B_SZ), 256, 0, stream>>>(ath, atl, woh, wol, b_out, out);
}

// Round 4
// 286.421 us; speedup vs baseline: 1.1495x; 1.1495x over previous
//
#include <hip/hip_runtime.h>
#include <hip/hip_bf16.h>
#include <stdint.h>

#define B_SZ 4
#define C_IN 256
#define N_SP 4096
#define HEADS 4
#define DH 32
#define HID 128

#define BI 128      // queries per block (4 waves x 32)
#define BJ 64       // keys per inner iteration
#define JHALF 2048  // keys per block (split-j x2)
#define PP 68       // P LDS row pitch in shorts (136 B, 8B-aligned, ~2-way banks)

typedef short short4v __attribute__((ext_vector_type(4)));
typedef short short8 __attribute__((ext_vector_type(8)));
typedef float f32x4 __attribute__((ext_vector_type(4)));

#if __has_builtin(__builtin_amdgcn_exp2f)
#define EXP2 __builtin_amdgcn_exp2f
#else
#define EXP2 exp2f
#endif

__device__ __forceinline__ short f2bfs(float f) {  // round-half-up f32->bf16
  return (short)((__float_as_uint(f) + 0x8000u) >> 16);
}
__device__ __forceinline__ float bfs2f(short s) {  // bf16->f32
  return __uint_as_float(((uint32_t)(unsigned short)s) << 16);
}
__device__ __forceinline__ short8 ld_frag(const short* p) {  // 8B-aligned 16B LDS read
  short4v a = *(const short4v*)p;
  short4v b = *(const short4v*)(p + 4);
  return __builtin_shufflevector(a, b, 0, 1, 2, 3, 4, 5, 6, 7);
}
__device__ __forceinline__ f32x4 mfma16(short8 a, short8 b, f32x4 c) {
  return __builtin_amdgcn_mfma_f32_16x16x32_bf16(a, b, c, 0, 0, 0);
}

// ---------------- Kernel 0: prep — transpose+split x -> bf16 hi/lo [b][n][c];
// convert w_qkv / w_out -> bf16 hi/lo ([o][c], k-contiguous).
__global__ __launch_bounds__(256) void prep_k(
    const float* __restrict__ x, const float* __restrict__ w_qkv,
    const float* __restrict__ w_out,
    short* __restrict__ xh, short* __restrict__ xl,
    short* __restrict__ wqh, short* __restrict__ wql,
    short* __restrict__ woh, short* __restrict__ wol) {
  const int t = threadIdx.x;
  const int bx = blockIdx.x;
  if (bx < 1024) {  // x transpose blocks: 64 n x 64 c per block
    __shared__ float T[64 * 65];  // [n][c-chunk], pitch 65 (2-way banks = free)
    const int b = bx >> 8, n0 = ((bx >> 2) & 63) * 64, c0 = (bx & 3) * 64;
    const float* xb = x + (size_t)b * C_IN * N_SP;
    {  // read 64c x 64n coalesced (wave reads 64 consecutive n at fixed c)
      const int n = t & 63, cw = t >> 6;
#pragma unroll
      for (int i = 0; i < 16; ++i) {
        const int c = cw * 16 + i;
        T[n * 65 + c] = xb[(size_t)(c0 + c) * N_SP + n0 + n];
      }
    }
    __syncthreads();
    {  // write hi/lo rows [n][c]: 16B stores, 4 lanes cover 32B/row
      const int n = t >> 2, cg = t & 3;
#pragma unroll
      for (int j = 0; j < 2; ++j) {
        const int c = cg * 16 + j * 8;
        short8 hv, lv;
#pragma unroll
        for (int e = 0; e < 8; ++e) {
          const float v = T[n * 65 + c + e];
          const short hh = f2bfs(v);
          hv[e] = hh;
          lv[e] = f2bfs(v - bfs2f(hh));
        }
        const size_t off = ((size_t)(b * N_SP + n0 + n)) * C_IN + c0 + c;
        *(short8*)(xh + off) = hv;
        *(short8*)(xl + off) = lv;
      }
    }
  } else {  // weight blocks: flat convert 131072 floats
    const int f0 = (bx - 1024) * 8192;
#pragma unroll
    for (int j = 0; j < 32; ++j) {
      const int f = f0 + j * 256 + t;
      float v;
      short *dh, *dl;
      int idx;
      if (f < 384 * 256) { v = w_qkv[f]; dh = wqh; dl = wql; idx = f; }
      else { idx = f - 384 * 256; v = w_out[idx]; dh = woh; dl = wol; }
      const short hh = f2bfs(v);
      dh[idx] = hh;
      dl[idx] = f2bfs(v - bfs2f(hh));
    }
  }
}

// ---------------- Kernel 1: QKV projection, bf16x3 MFMA (unchanged) ----------------
__global__ __launch_bounds__(256) void qkv_mfma_k(
    const short* __restrict__ xh, const short* __restrict__ xl,
    const short* __restrict__ wqh, const short* __restrict__ wql,
    short* __restrict__ qt, short* __restrict__ kt, short* __restrict__ vt) {
  const int t = threadIdx.x;
  const int lane = t & 63, w = t >> 6;
  const int l15 = lane & 15, quad = lane >> 4;
  const int osec = blockIdx.y, b = blockIdx.z;
  const int n0 = blockIdx.x * 64 + w * 16;
  const size_t xrow = ((size_t)(b * N_SP + n0 + l15)) * C_IN;
  const size_t wrow = ((size_t)(osec * 128 + l15)) * C_IN;
  const bool isv = (osec == 2);
  const f32x4 zz = {0.f, 0.f, 0.f, 0.f};
  f32x4 acc[8];
#pragma unroll
  for (int ot = 0; ot < 8; ++ot) acc[ot] = zz;

  for (int k0 = 0; k0 < C_IN; k0 += 32) {
    const int ko = k0 + quad * 8;
    const short8 xhf = *(const short8*)(xh + xrow + ko);
    const short8 xlf = *(const short8*)(xl + xrow + ko);
#pragma unroll
    for (int ot = 0; ot < 8; ++ot) {
      const size_t wo = wrow + (size_t)ot * 16 * C_IN + ko;
      const short8 whf = *(const short8*)(wqh + wo);
      const short8 wlf = *(const short8*)(wql + wo);
      if (isv) {  // A = x (rows n), B = w (rows o)
        acc[ot] = mfma16(xhf, whf, acc[ot]);
        acc[ot] = mfma16(xlf, whf, acc[ot]);
        acc[ot] = mfma16(xhf, wlf, acc[ot]);
      } else {    // A = w (rows o), B = x (rows n)
        acc[ot] = mfma16(whf, xhf, acc[ot]);
        acc[ot] = mfma16(whf, xlf, acc[ot]);
        acc[ot] = mfma16(wlf, xhf, acc[ot]);
      }
    }
  }

  if (!isv) {  // lane holds o = osec*128 + ot*16 + quad*4 + r, n = n0 + l15
    const float sc = osec ? 1.f : (0.17677669529663687f * 1.4426950408889634f);
    short* dst = osec ? kt : qt;
    const int n = n0 + l15;
#pragma unroll
    for (int ot = 0; ot < 8; ++ot) {
      const int ol = ot * 16 + quad * 4;
      const int h = ol >> 5, d0 = ol & 31;
      short4v p;
#pragma unroll
      for (int r = 0; r < 4; ++r) p[r] = f2bfs(acc[ot][r] * sc);
      *(short4v*)(dst + ((size_t)(b * HEADS + h) * N_SP + n) * DH + d0) = p;
    }
  } else {     // lane holds n = n0 + quad*4 + r, o = 256 + ot*16 + l15
    const int n = n0 + quad * 4;
#pragma unroll
    for (int ot = 0; ot < 8; ++ot) {
      const int ol = ot * 16 + l15;
      const int h = ol >> 5, d = ol & 31;
      short4v p;
#pragma unroll
      for (int r = 0; r < 4; ++r) p[r] = f2bfs(acc[ot][r]);
      *(short4v*)(vt + ((size_t)(b * HEADS + h) * DH + d) * N_SP + n) = p;
    }
  }
}

// ---------------- Kernel 2: flash attention, split-j x2, partial O/l out -------
// BI=128 (round-0 intensity) x 2 j-parts: grid (32,16,2) = 1024 blocks = 4/CU.
// o_acc[tt][dt][r] = O[i = w*32+tt*16+quad*4+r][d = dt*16+l15]  (A-rows->D-rows!)
// -> Osh[d][i] LDS transpose (round-0 proven), then po[n][hid] f32 16B stores.
__global__ __launch_bounds__(256, 4) void attn_k(
    const short* __restrict__ qt, const short* __restrict__ kt,
    const short* __restrict__ vt, float* __restrict__ po,
    float* __restrict__ lws) {
  __shared__ short Ps[BI * PP];    // 17408 B, [i][j] bf16, rows owned per-wave
  __shared__ float Osh[DH * 132];  // 16896 B, epilogue transpose
  const int t = threadIdx.x;
  const int lane = t & 63, w = t >> 6;
  const int l15 = lane & 15, quad = lane >> 4;
  const int i0 = blockIdx.x * BI;
  const int bh = blockIdx.y;
  const int part = blockIdx.z;
  const int jbase = part * JHALF;
  const short* qg = qt + ((size_t)bh * N_SP + i0) * DH;
  const short* kg = kt + ((size_t)bh * N_SP + jbase) * DH;  // part-local K
  const short* vg = vt + (size_t)bh * DH * N_SP + jbase;    // part-local V cols

  // Q fragments (loop-invariant): B[n=i][k=d]
  short8 bq[2];
#pragma unroll
  for (int tt = 0; tt < 2; ++tt)
    bq[tt] = *(const short8*)(qg + (size_t)(w * 32 + tt * 16 + l15) * DH + quad * 8);

  const f32x4 zz = {0.f, 0.f, 0.f, 0.f};
  f32x4 o_acc[2][2] = {{zz, zz}, {zz, zz}};  // [tt][dt]
  float lsum[2] = {0.f, 0.f};
  short* prow[2];
#pragma unroll
  for (int tt = 0; tt < 2; ++tt) prow[tt] = Ps + (w * 32 + tt * 16 + l15) * PP;

  short8 akA[4], akB[4], vbA[2][2], vbB[2][2];
#pragma unroll
  for (int jt = 0; jt < 4; ++jt)
    akA[jt] = *(const short8*)(kg + (size_t)(jt * 16 + l15) * DH + quad * 8);
#pragma unroll
  for (int dt = 0; dt < 2; ++dt)
#pragma unroll
    for (int kk = 0; kk < 2; ++kk)
      vbA[dt][kk] = *(const short8*)(vg + (size_t)(dt * 16 + l15) * N_SP + kk * 32 + quad * 8);

  auto body = [&](const short8 (&akc)[4], const short8 (&vbc)[2][2],
                  short8 (&akn)[4], short8 (&vbn)[2][2], int jn) {
    // S^T tiles: D[j][i] = mfma(K, Q)
    f32x4 sf[2][4];
    __builtin_amdgcn_s_setprio(1);
#pragma unroll
    for (int tt = 0; tt < 2; ++tt)
#pragma unroll
      for (int jt = 0; jt < 4; ++jt) sf[tt][jt] = mfma16(akc[jt], bq[tt], zz);
    __builtin_amdgcn_s_setprio(0);
    // prefetch next tile's K/V into the alternate register set
#pragma unroll
    for (int jt = 0; jt < 4; ++jt)
      akn[jt] = *(const short8*)(kg + (size_t)(jn + jt * 16 + l15) * DH + quad * 8);
#pragma unroll
    for (int dt = 0; dt < 2; ++dt)
#pragma unroll
      for (int kk = 0; kk < 2; ++kk)
        vbn[dt][kk] = *(const short8*)(vg + (size_t)(dt * 16 + l15) * N_SP + jn + kk * 32 + quad * 8);
    // exp2 (no max), accumulate l, pack P[i][j] via v_cvt_pk_bf16_f32
#pragma unroll
    for (int tt = 0; tt < 2; ++tt)
#pragma unroll
      for (int jt = 0; jt < 4; ++jt) {
        const float e0 = EXP2(sf[tt][jt][0]);
        const float e1 = EXP2(sf[tt][jt][1]);
        const float e2 = EXP2(sf[tt][jt][2]);
        const float e3 = EXP2(sf[tt][jt][3]);
        lsum[tt] += (e0 + e1) + (e2 + e3);
        uint2 pk;
        asm("v_cvt_pk_bf16_f32 %0, %1, %2" : "=v"(pk.x) : "v"(e0), "v"(e1));
        asm("v_cvt_pk_bf16_f32 %0, %1, %2" : "=v"(pk.y) : "v"(e2), "v"(e3));
        *(uint2*)(prow[tt] + jt * 16 + quad * 4) = pk;
      }
    asm volatile("s_waitcnt lgkmcnt(0)" ::: "memory");  // same-wave P write->read
    // O += P V^T
    short8 pa[2][2];
#pragma unroll
    for (int tt = 0; tt < 2; ++tt)
#pragma unroll
      for (int kk = 0; kk < 2; ++kk) pa[tt][kk] = ld_frag(prow[tt] + kk * 32 + quad * 8);
    __builtin_amdgcn_s_setprio(1);
#pragma unroll
    for (int tt = 0; tt < 2; ++tt)
#pragma unroll
      for (int dt = 0; dt < 2; ++dt) {
        o_acc[tt][dt] = mfma16(pa[tt][0], vbc[dt][0], o_acc[tt][dt]);
        o_acc[tt][dt] = mfma16(pa[tt][1], vbc[dt][1], o_acc[tt][dt]);
      }
    __builtin_amdgcn_s_setprio(0);
  };

  for (int jo = 0; jo < JHALF; jo += 2 * BJ) {
    body(akA, vbA, akB, vbB, (jo + BJ) & (JHALF - 1));
    body(akB, vbB, akA, vbA, (jo + 2 * BJ) & (JHALF - 1));
  }

  // reduce l over quads (lanes sharing l15) and store partial l (per i = l15)
#pragma unroll
  for (int tt = 0; tt < 2; ++tt) {
    lsum[tt] += __shfl_xor(lsum[tt], 16);
    lsum[tt] += __shfl_xor(lsum[tt], 32);
  }
  if (lane < 16) {
#pragma unroll
    for (int tt = 0; tt < 2; ++tt)
      lws[((size_t)(part * 16 + bh)) * N_SP + i0 + w * 32 + tt * 16 + lane] = lsum[tt];
  }
  // transpose unnormalized partial O to Osh[d][i] (correct D mapping)
#pragma unroll
  for (int tt = 0; tt < 2; ++tt)
#pragma unroll
    for (int dt = 0; dt < 2; ++dt)
#pragma unroll
      for (int r = 0; r < 4; ++r)
        Osh[(dt * 16 + l15) * 132 + w * 32 + tt * 16 + quad * 4 + r] = o_acc[tt][dt][r];
  __syncthreads();
  {  // store po[part][b][n][hid] f32: thread owns (row ii, 16-d half), 16B stores
    const int ii = t & 127, half = t >> 7;
    const int b = bh >> 2, h = bh & 3;
    float* dst = po + ((size_t)((part * B_SZ + b) * N_SP) + i0 + ii) * HID +
                 h * 32 + half * 16;
#pragma unroll
    for (int j4 = 0; j4 < 4; ++j4) {
      float4 vv;
      vv.x = Osh[(half * 16 + j4 * 4 + 0) * 132 + ii];
      vv.y = Osh[(half * 16 + j4 * 4 + 1) * 132 + ii];
      vv.z = Osh[(half * 16 + j4 * 4 + 2) * 132 + ii];
      vv.w = Osh[(half * 16 + j4 * 4 + 3) * 132 + ii];
      *(float4*)(dst + j4 * 4) = vv;
    }
  }
}

// ---------------- Kernel 3: combine partials + output projection, bf16x3 MFMA ----
// grid (64 ntiles, 2 osec, 4 b); wave = 16 n, 128 o. A-fragment built inline:
// a = (po0 + po1) * (1/(l0+l1)) -> bf16 hi/lo, amortized over 8 o-tiles.
__global__ __launch_bounds__(256) void out_mfma_k(
    const float* __restrict__ po, const float* __restrict__ lws,
    const short* __restrict__ woh, const short* __restrict__ wol,
    const float* __restrict__ bias, float* __restrict__ out) {
  const int t = threadIdx.x;
  const int lane = t & 63, w = t >> 6;
  const int l15 = lane & 15, quad = lane >> 4;
  const int osec = blockIdx.y, b = blockIdx.z;
  const int n0 = blockIdx.x * 64 + w * 16;
  const int n = n0 + l15;
  const size_t PSTR = (size_t)B_SZ * N_SP * HID;
  const float* arow = po + ((size_t)(b * N_SP) + n) * HID;
  const size_t wrow = ((size_t)(osec * 128 + l15)) * HID;
  const f32x4 zz = {0.f, 0.f, 0.f, 0.f};
  f32x4 acc[8];
#pragma unroll
  for (int ot = 0; ot < 8; ++ot) acc[ot] = zz;

  for (int k0 = 0; k0 < HID; k0 += 32) {
    const int ko = k0 + quad * 8;
    const int h = k0 >> 5;
    const int bh = b * HEADS + h;
    const float lv = lws[(size_t)bh * N_SP + n] + lws[(size_t)(16 + bh) * N_SP + n];
    const float linv = 1.f / lv;
    const float* pr = arow + ko;
    const float4 u0 = *(const float4*)(pr);
    const float4 u1 = *(const float4*)(pr + 4);
    const float4 v0 = *(const float4*)(pr + PSTR);
    const float4 v1 = *(const float4*)(pr + PSTR + 4);
    const float av[8] = {(u0.x + v0.x) * linv, (u0.y + v0.y) * linv,
                         (u0.z + v0.z) * linv, (u0.w + v0.w) * linv,
                         (u1.x + v1.x) * linv, (u1.y + v1.y) * linv,
                         (u1.z + v1.z) * linv, (u1.w + v1.w) * linv};
    short8 ahf, alf;
#pragma unroll
    for (int e = 0; e < 8; ++e) {
      const short hh = f2bfs(av[e]);
      ahf[e] = hh;
      alf[e] = f2bfs(av[e] - bfs2f(hh));
    }
#pragma unroll
    for (int ot = 0; ot < 8; ++ot) {
      const size_t wo = wrow + (size_t)ot * 16 * HID + ko;
      const short8 whf = *(const short8*)(woh + wo);
      const short8 wlf = *(const short8*)(wol + wo);
      acc[ot] = mfma16(ahf, whf, acc[ot]);
      acc[ot] = mfma16(alf, whf, acc[ot]);
      acc[ot] = mfma16(ahf, wlf, acc[ot]);
    }
  }
  // lane holds n = n0 + quad*4 + r, o = osec*128 + ot*16 + l15
#pragma unroll
  for (int ot = 0; ot < 8; ++ot) {
    const int o = osec * 128 + ot * 16 + l15;
    const float bv = bias[o];
    float4 v = make_float4(acc[ot][0] + bv, acc[ot][1] + bv,
                           acc[ot][2] + bv, acc[ot][3] + bv);
    *(float4*)(out + ((size_t)(b * C_IN + o)) * N_SP + n0 + quad * 4) = v;
  }
}

extern "C" void kernel_launch(void* const* d_in, const int* in_sizes, int n_in,
                              void* d_out, int out_size, void* d_ws, size_t ws_size,
                              hipStream_t stream) {
  const float* x = (const float*)d_in[0];
  const float* w_qkv = (const float*)d_in[1];
  const float* w_out = (const float*)d_in[2];
  const float* b_out = (const float*)d_in[3];
  float* out = (float*)d_out;

  // workspace layout, ~30.4 MiB total:
  short* xh = (short*)d_ws;                         // 4*4096*256 shorts = 8.39 MB
  short* xl = xh + (size_t)B_SZ * N_SP * C_IN;      // 8.39 MB
  short* wqh = xl + (size_t)B_SZ * N_SP * C_IN;     // 384*256*2B
  short* wql = wqh + 384 * C_IN;
  short* woh = wql + 384 * C_IN;                    // 256*128*2B
  short* wol = woh + C_IN * HID;
  short* qt = wol + C_IN * HID;                     // 16*4096*32 = 4 MB
  short* kt = qt + (size_t)16 * N_SP * DH;          // 4 MB
  short* vt = kt + (size_t)16 * N_SP * DH;          // 4 MB
  float* lws = (float*)(vt + (size_t)16 * N_SP * DH);  // 2*16*4096 f32 = 512 KB
  float* po = (float*)xh;  // partial O: 2*4*4096*128 f32 = 16.78 MB = xh+xl exactly

  prep_k<<<dim3(1040), 256, 0, stream>>>(x, w_qkv, w_out, xh, xl, wqh, wql, woh, wol);
  qkv_mfma_k<<<dim3(64, 3, B_SZ), 256, 0, stream>>>(xh, xl, wqh, wql, qt, kt, vt);
  attn_k<<<dim3(N_SP / BI, B_SZ * HEADS, 2), 256, 0, stream>>>(qt, kt, vt, po, lws);
  out_mfma_k<<<dim3(64, 2, B_SZ), 256, 0, stream>>>(po, lws, woh, wol, b_out, out);
}

// Round 5
// 253.189 us; speedup vs baseline: 1.3004x; 1.1313x over previous
//
#include <hip/hip_runtime.h>
#include <hip/hip_bf16.h>
#include <stdint.h>

#define B_SZ 4
#define C_IN 256
#define N_SP 4096
#define HEADS 4
#define DH 32
#define HID 128

#define BI 128      // queries per block (4 waves x 32)
#define BJ 64       // keys per inner iteration
#define JHALF 2048  // keys per block (split-j x2)
#define PP 68       // P LDS row pitch in shorts (136 B, 8B-aligned, ~2-way banks)

typedef short short4v __attribute__((ext_vector_type(4)));
typedef short short8 __attribute__((ext_vector_type(8)));
typedef float f32x4 __attribute__((ext_vector_type(4)));

#if __has_builtin(__builtin_amdgcn_exp2f)
#define EXP2 __builtin_amdgcn_exp2f
#else
#define EXP2 exp2f
#endif

__device__ __forceinline__ short f2bfs(float f) {  // round-half-up f32->bf16
  return (short)((__float_as_uint(f) + 0x8000u) >> 16);
}
__device__ __forceinline__ float bfs2f(short s) {  // bf16->f32
  return __uint_as_float(((uint32_t)(unsigned short)s) << 16);
}
__device__ __forceinline__ short8 ld_frag(const short* p) {  // 8B-aligned 16B LDS read
  short4v a = *(const short4v*)p;
  short4v b = *(const short4v*)(p + 4);
  return __builtin_shufflevector(a, b, 0, 1, 2, 3, 4, 5, 6, 7);
}
__device__ __forceinline__ f32x4 mfma16(short8 a, short8 b, f32x4 c) {
  return __builtin_amdgcn_mfma_f32_16x16x32_bf16(a, b, c, 0, 0, 0);
}

// ---------------- Kernel 0: prep — transpose+split x -> bf16 hi/lo [b][n][c];
// convert w_qkv / w_out -> bf16 hi/lo ([o][c], k-contiguous).
__global__ __launch_bounds__(256) void prep_k(
    const float* __restrict__ x, const float* __restrict__ w_qkv,
    const float* __restrict__ w_out,
    short* __restrict__ xh, short* __restrict__ xl,
    short* __restrict__ wqh, short* __restrict__ wql,
    short* __restrict__ woh, short* __restrict__ wol) {
  const int t = threadIdx.x;
  const int bx = blockIdx.x;
  if (bx < 1024) {  // x transpose blocks: 64 n x 64 c per block
    __shared__ float T[64 * 65];  // [n][c-chunk], pitch 65 (2-way banks = free)
    const int b = bx >> 8, n0 = ((bx >> 2) & 63) * 64, c0 = (bx & 3) * 64;
    const float* xb = x + (size_t)b * C_IN * N_SP;
    {  // read 64c x 64n coalesced (wave reads 64 consecutive n at fixed c)
      const int n = t & 63, cw = t >> 6;
#pragma unroll
      for (int i = 0; i < 16; ++i) {
        const int c = cw * 16 + i;
        T[n * 65 + c] = xb[(size_t)(c0 + c) * N_SP + n0 + n];
      }
    }
    __syncthreads();
    {  // write hi/lo rows [n][c]: 16B stores, 4 lanes cover 32B/row
      const int n = t >> 2, cg = t & 3;
#pragma unroll
      for (int j = 0; j < 2; ++j) {
        const int c = cg * 16 + j * 8;
        short8 hv, lv;
#pragma unroll
        for (int e = 0; e < 8; ++e) {
          const float v = T[n * 65 + c + e];
          const short hh = f2bfs(v);
          hv[e] = hh;
          lv[e] = f2bfs(v - bfs2f(hh));
        }
        const size_t off = ((size_t)(b * N_SP + n0 + n)) * C_IN + c0 + c;
        *(short8*)(xh + off) = hv;
        *(short8*)(xl + off) = lv;
      }
    }
  } else {  // weight blocks: flat convert 131072 floats
    const int f0 = (bx - 1024) * 8192;
#pragma unroll
    for (int j = 0; j < 32; ++j) {
      const int f = f0 + j * 256 + t;
      float v;
      short *dh, *dl;
      int idx;
      if (f < 384 * 256) { v = w_qkv[f]; dh = wqh; dl = wql; idx = f; }
      else { idx = f - 384 * 256; v = w_out[idx]; dh = woh; dl = wol; }
      const short hh = f2bfs(v);
      dh[idx] = hh;
      dl[idx] = f2bfs(v - bfs2f(hh));
    }
  }
}

// ---------------- Kernel 1: QKV projection, bf16x3 MFMA (unchanged) ----------------
__global__ __launch_bounds__(256) void qkv_mfma_k(
    const short* __restrict__ xh, const short* __restrict__ xl,
    const short* __restrict__ wqh, const short* __restrict__ wql,
    short* __restrict__ qt, short* __restrict__ kt, short* __restrict__ vt) {
  const int t = threadIdx.x;
  const int lane = t & 63, w = t >> 6;
  const int l15 = lane & 15, quad = lane >> 4;
  const int osec = blockIdx.y, b = blockIdx.z;
  const int n0 = blockIdx.x * 64 + w * 16;
  const size_t xrow = ((size_t)(b * N_SP + n0 + l15)) * C_IN;
  const size_t wrow = ((size_t)(osec * 128 + l15)) * C_IN;
  const bool isv = (osec == 2);
  const f32x4 zz = {0.f, 0.f, 0.f, 0.f};
  f32x4 acc[8];
#pragma unroll
  for (int ot = 0; ot < 8; ++ot) acc[ot] = zz;

  for (int k0 = 0; k0 < C_IN; k0 += 32) {
    const int ko = k0 + quad * 8;
    const short8 xhf = *(const short8*)(xh + xrow + ko);
    const short8 xlf = *(const short8*)(xl + xrow + ko);
#pragma unroll
    for (int ot = 0; ot < 8; ++ot) {
      const size_t wo = wrow + (size_t)ot * 16 * C_IN + ko;
      const short8 whf = *(const short8*)(wqh + wo);
      const short8 wlf = *(const short8*)(wql + wo);
      if (isv) {  // A = x (rows n), B = w (rows o)
        acc[ot] = mfma16(xhf, whf, acc[ot]);
        acc[ot] = mfma16(xlf, whf, acc[ot]);
        acc[ot] = mfma16(xhf, wlf, acc[ot]);
      } else {    // A = w (rows o), B = x (rows n)
        acc[ot] = mfma16(whf, xhf, acc[ot]);
        acc[ot] = mfma16(whf, xlf, acc[ot]);
        acc[ot] = mfma16(wlf, xhf, acc[ot]);
      }
    }
  }

  if (!isv) {  // lane holds o = osec*128 + ot*16 + quad*4 + r, n = n0 + l15
    const float sc = osec ? 1.f : (0.17677669529663687f * 1.4426950408889634f);
    short* dst = osec ? kt : qt;
    const int n = n0 + l15;
#pragma unroll
    for (int ot = 0; ot < 8; ++ot) {
      const int ol = ot * 16 + quad * 4;
      const int h = ol >> 5, d0 = ol & 31;
      short4v p;
#pragma unroll
      for (int r = 0; r < 4; ++r) p[r] = f2bfs(acc[ot][r] * sc);
      *(short4v*)(dst + ((size_t)(b * HEADS + h) * N_SP + n) * DH + d0) = p;
    }
  } else {     // lane holds n = n0 + quad*4 + r, o = 256 + ot*16 + l15
    const int n = n0 + quad * 4;
#pragma unroll
    for (int ot = 0; ot < 8; ++ot) {
      const int ol = ot * 16 + l15;
      const int h = ol >> 5, d = ol & 31;
      short4v p;
#pragma unroll
      for (int r = 0; r < 4; ++r) p[r] = f2bfs(acc[ot][r]);
      *(short4v*)(vt + ((size_t)(b * HEADS + h) * DH + d) * N_SP + n) = p;
    }
  }
}

// ---------------- Kernel 2: flash attention, split-j x2, partial O/l out -------
// BI=128 x 2 j-parts: grid (32,16,2) = 1024 blocks = 4/CU.
// __launch_bounds__(256, 2): round-4's (256,4) shrank VGPR 88->64, demoting the
// K/V prefetch double-buffer to reloads (VALUBusy 37->19, attn 101->137 µs).
// (256,2) keeps the pipeline live (~88-96 VGPR <= 128 -> still 4 waves/SIMD).
__global__ __launch_bounds__(256, 2) void attn_k(
    const short* __restrict__ qt, const short* __restrict__ kt,
    const short* __restrict__ vt, float* __restrict__ po,
    float* __restrict__ lws) {
  __shared__ short Ps[BI * PP];    // 17408 B, [i][j] bf16, rows owned per-wave
  __shared__ float Osh[DH * 132];  // 16896 B, epilogue transpose
  const int t = threadIdx.x;
  const int lane = t & 63, w = t >> 6;
  const int l15 = lane & 15, quad = lane >> 4;
  const int i0 = blockIdx.x * BI;
  const int bh = blockIdx.y;
  const int part = blockIdx.z;
  const int jbase = part * JHALF;
  const short* qg = qt + ((size_t)bh * N_SP + i0) * DH;
  const short* kg = kt + ((size_t)bh * N_SP + jbase) * DH;  // part-local K
  const short* vg = vt + (size_t)bh * DH * N_SP + jbase;    // part-local V cols

  // Q fragments (loop-invariant): B[n=i][k=d]
  short8 bq[2];
#pragma unroll
  for (int tt = 0; tt < 2; ++tt)
    bq[tt] = *(const short8*)(qg + (size_t)(w * 32 + tt * 16 + l15) * DH + quad * 8);

  const f32x4 zz = {0.f, 0.f, 0.f, 0.f};
  f32x4 o_acc[2][2] = {{zz, zz}, {zz, zz}};  // [tt][dt]
  float lsum[2] = {0.f, 0.f};
  short* prow[2];
#pragma unroll
  for (int tt = 0; tt < 2; ++tt) prow[tt] = Ps + (w * 32 + tt * 16 + l15) * PP;

  short8 akA[4], akB[4], vbA[2][2], vbB[2][2];
#pragma unroll
  for (int jt = 0; jt < 4; ++jt)
    akA[jt] = *(const short8*)(kg + (size_t)(jt * 16 + l15) * DH + quad * 8);
#pragma unroll
  for (int dt = 0; dt < 2; ++dt)
#pragma unroll
    for (int kk = 0; kk < 2; ++kk)
      vbA[dt][kk] = *(const short8*)(vg + (size_t)(dt * 16 + l15) * N_SP + kk * 32 + quad * 8);

  auto body = [&](const short8 (&akc)[4], const short8 (&vbc)[2][2],
                  short8 (&akn)[4], short8 (&vbn)[2][2], int jn) {
    // S^T tiles: D[j][i] = mfma(K, Q)
    f32x4 sf[2][4];
    __builtin_amdgcn_s_setprio(1);
#pragma unroll
    for (int tt = 0; tt < 2; ++tt)
#pragma unroll
      for (int jt = 0; jt < 4; ++jt) sf[tt][jt] = mfma16(akc[jt], bq[tt], zz);
    __builtin_amdgcn_s_setprio(0);
    // prefetch next tile's K/V into the alternate register set
#pragma unroll
    for (int jt = 0; jt < 4; ++jt)
      akn[jt] = *(const short8*)(kg + (size_t)(jn + jt * 16 + l15) * DH + quad * 8);
#pragma unroll
    for (int dt = 0; dt < 2; ++dt)
#pragma unroll
      for (int kk = 0; kk < 2; ++kk)
        vbn[dt][kk] = *(const short8*)(vg + (size_t)(dt * 16 + l15) * N_SP + jn + kk * 32 + quad * 8);
    // exp2 (no max), accumulate l, pack P[i][j] via v_cvt_pk_bf16_f32
#pragma unroll
    for (int tt = 0; tt < 2; ++tt)
#pragma unroll
      for (int jt = 0; jt < 4; ++jt) {
        const float e0 = EXP2(sf[tt][jt][0]);
        const float e1 = EXP2(sf[tt][jt][1]);
        const float e2 = EXP2(sf[tt][jt][2]);
        const float e3 = EXP2(sf[tt][jt][3]);
        lsum[tt] += (e0 + e1) + (e2 + e3);
        uint2 pk;
        asm("v_cvt_pk_bf16_f32 %0, %1, %2" : "=v"(pk.x) : "v"(e0), "v"(e1));
        asm("v_cvt_pk_bf16_f32 %0, %1, %2" : "=v"(pk.y) : "v"(e2), "v"(e3));
        *(uint2*)(prow[tt] + jt * 16 + quad * 4) = pk;
      }
    asm volatile("s_waitcnt lgkmcnt(0)" ::: "memory");  // same-wave P write->read
    // O += P V^T
    short8 pa[2][2];
#pragma unroll
    for (int tt = 0; tt < 2; ++tt)
#pragma unroll
      for (int kk = 0; kk < 2; ++kk) pa[tt][kk] = ld_frag(prow[tt] + kk * 32 + quad * 8);
    __builtin_amdgcn_s_setprio(1);
#pragma unroll
    for (int tt = 0; tt < 2; ++tt)
#pragma unroll
      for (int dt = 0; dt < 2; ++dt) {
        o_acc[tt][dt] = mfma16(pa[tt][0], vbc[dt][0], o_acc[tt][dt]);
        o_acc[tt][dt] = mfma16(pa[tt][1], vbc[dt][1], o_acc[tt][dt]);
      }
    __builtin_amdgcn_s_setprio(0);
  };

  for (int jo = 0; jo < JHALF; jo += 2 * BJ) {
    body(akA, vbA, akB, vbB, (jo + BJ) & (JHALF - 1));
    body(akB, vbB, akA, vbA, (jo + 2 * BJ) & (JHALF - 1));
  }

  // reduce l over quads (lanes sharing l15) and store partial l (per i = l15)
#pragma unroll
  for (int tt = 0; tt < 2; ++tt) {
    lsum[tt] += __shfl_xor(lsum[tt], 16);
    lsum[tt] += __shfl_xor(lsum[tt], 32);
  }
  if (lane < 16) {
#pragma unroll
    for (int tt = 0; tt < 2; ++tt)
      lws[((size_t)(part * 16 + bh)) * N_SP + i0 + w * 32 + tt * 16 + lane] = lsum[tt];
  }
  // transpose unnormalized partial O to Osh[d][i] (correct D mapping)
#pragma unroll
  for (int tt = 0; tt < 2; ++tt)
#pragma unroll
    for (int dt = 0; dt < 2; ++dt)
#pragma unroll
      for (int r = 0; r < 4; ++r)
        Osh[(dt * 16 + l15) * 132 + w * 32 + tt * 16 + quad * 4 + r] = o_acc[tt][dt][r];
  __syncthreads();
  {  // store po[part][b][n][hid] f32: thread owns (row ii, 16-d half), 16B stores
    const int ii = t & 127, half = t >> 7;
    const int b = bh >> 2, h = bh & 3;
    float* dst = po + ((size_t)((part * B_SZ + b) * N_SP) + i0 + ii) * HID +
                 h * 32 + half * 16;
#pragma unroll
    for (int j4 = 0; j4 < 4; ++j4) {
      float4 vv;
      vv.x = Osh[(half * 16 + j4 * 4 + 0) * 132 + ii];
      vv.y = Osh[(half * 16 + j4 * 4 + 1) * 132 + ii];
      vv.z = Osh[(half * 16 + j4 * 4 + 2) * 132 + ii];
      vv.w = Osh[(half * 16 + j4 * 4 + 3) * 132 + ii];
      *(float4*)(dst + j4 * 4) = vv;
    }
  }
}

// ---------------- Kernel 3: combine partials + output projection, bf16x3 MFMA ----
// grid (64 ntiles, 2 osec, 4 b); wave = 16 n, 128 o. A-fragment built inline:
// a = (po0 + po1) * (1/(l0+l1)) -> bf16 hi/lo, amortized over 8 o-tiles.
__global__ __launch_bounds__(256) void out_mfma_k(
    const float* __restrict__ po, const float* __restrict__ lws,
    const short* __restrict__ woh, const short* __restrict__ wol,
    const float* __restrict__ bias, float* __restrict__ out) {
  const int t = threadIdx.x;
  const int lane = t & 63, w = t >> 6;
  const int l15 = lane & 15, quad = lane >> 4;
  const int osec = blockIdx.y, b = blockIdx.z;
  const int n0 = blockIdx.x * 64 + w * 16;
  const int n = n0 + l15;
  const size_t PSTR = (size_t)B_SZ * N_SP * HID;
  const float* arow = po + ((size_t)(b * N_SP) + n) * HID;
  const size_t wrow = ((size_t)(osec * 128 + l15)) * HID;
  const f32x4 zz = {0.f, 0.f, 0.f, 0.f};
  f32x4 acc[8];
#pragma unroll
  for (int ot = 0; ot < 8; ++ot) acc[ot] = zz;

  for (int k0 = 0; k0 < HID; k0 += 32) {
    const int ko = k0 + quad * 8;
    const int h = k0 >> 5;
    const int bh = b * HEADS + h;
    const float lv = lws[(size_t)bh * N_SP + n] + lws[(size_t)(16 + bh) * N_SP + n];
    const float linv = 1.f / lv;
    const float* pr = arow + ko;
    const float4 u0 = *(const float4*)(pr);
    const float4 u1 = *(const float4*)(pr + 4);
    const float4 v0 = *(const float4*)(pr + PSTR);
    const float4 v1 = *(const float4*)(pr + PSTR + 4);
    const float av[8] = {(u0.x + v0.x) * linv, (u0.y + v0.y) * linv,
                         (u0.z + v0.z) * linv, (u0.w + v0.w) * linv,
                         (u1.x + v1.x) * linv, (u1.y + v1.y) * linv,
                         (u1.z + v1.z) * linv, (u1.w + v1.w) * linv};
    short8 ahf, alf;
#pragma unroll
    for (int e = 0; e < 8; ++e) {
      const short hh = f2bfs(av[e]);
      ahf[e] = hh;
      alf[e] = f2bfs(av[e] - bfs2f(hh));
    }
#pragma unroll
    for (int ot = 0; ot < 8; ++ot) {
      const size_t wo = wrow + (size_t)ot * 16 * HID + ko;
      const short8 whf = *(const short8*)(woh + wo);
      const short8 wlf = *(const short8*)(wol + wo);
      acc[ot] = mfma16(ahf, whf, acc[ot]);
      acc[ot] = mfma16(alf, whf, acc[ot]);
      acc[ot] = mfma16(ahf, wlf, acc[ot]);
    }
  }
  // lane holds n = n0 + quad*4 + r, o = osec*128 + ot*16 + l15
#pragma unroll
  for (int ot = 0; ot < 8; ++ot) {
    const int o = osec * 128 + ot * 16 + l15;
    const float bv = bias[o];
    float4 v = make_float4(acc[ot][0] + bv, acc[ot][1] + bv,
                           acc[ot][2] + bv, acc[ot][3] + bv);
    *(float4*)(out + ((size_t)(b * C_IN + o)) * N_SP + n0 + quad * 4) = v;
  }
}

extern "C" void kernel_launch(void* const* d_in, const int* in_sizes, int n_in,
                              void* d_out, int out_size, void* d_ws, size_t ws_size,
                              hipStream_t stream) {
  const float* x = (const float*)d_in[0];
  const float* w_qkv = (const float*)d_in[1];
  const float* w_out = (const float*)d_in[2];
  const float* b_out = (const float*)d_in[3];
  float* out = (float*)d_out;

  // workspace layout, ~30.4 MiB total:
  short* xh = (short*)d_ws;                         // 4*4096*256 shorts = 8.39 MB
  short* xl = xh + (size_t)B_SZ * N_SP * C_IN;      // 8.39 MB
  short* wqh = xl + (size_t)B_SZ * N_SP * C_IN;     // 384*256*2B
  short* wql = wqh + 384 * C_IN;
  short* woh = wql + 384 * C_IN;                    // 256*128*2B
  short* wol = woh + C_IN * HID;
  short* qt = wol + C_IN * HID;                     // 16*4096*32 = 4 MB
  short* kt = qt + (size_t)16 * N_SP * DH;          // 4 MB
  short* vt = kt + (size_t)16 * N_SP * DH;          // 4 MB
  float* lws = (float*)(vt + (size_t)16 * N_SP * DH);  // 2*16*4096 f32 = 512 KB
  float* po = (float*)xh;  // partial O: 2*4*4096*128 f32 = 16.78 MB = xh+xl exactly

  prep_k<<<dim3(1040), 256, 0, stream>>>(x, w_qkv, w_out, xh, xl, wqh, wql, woh, wol);
  qkv_mfma_k<<<dim3(64, 3, B_SZ), 256, 0, stream>>>(xh, xl, wqh, wql, qt, kt, vt);
  attn_k<<<dim3(N_SP / BI, B_SZ * HEADS, 2), 256, 0, stream>>>(qt, kt, vt, po, lws);
  out_mfma_k<<<dim3(64, 2, B_SZ), 256, 0, stream>>>(po, lws, woh, wol, b_out, out);
}

// Round 6
// 248.736 us; speedup vs baseline: 1.3237x; 1.0179x over previous
//
#include <hip/hip_runtime.h>
#include <hip/hip_bf16.h>
#include <stdint.h>

#define B_SZ 4
#define C_IN 256
#define N_SP 4096
#define HEADS 4
#define DH 32
#define HID 128

#define BI 128      // queries per block (4 waves x 32)
#define BJ 64       // keys per inner iteration
#define JHALF 2048  // keys per block (split-j x2)
#define PP 68       // P LDS row pitch in shorts (136 B, 8B-aligned, ~2-way banks)

typedef short short4v __attribute__((ext_vector_type(4)));
typedef short short8 __attribute__((ext_vector_type(8)));
typedef float f32x4 __attribute__((ext_vector_type(4)));

#if __has_builtin(__builtin_amdgcn_exp2f)
#define EXP2 __builtin_amdgcn_exp2f
#else
#define EXP2 exp2f
#endif

__device__ __forceinline__ short f2bfs(float f) {  // round-half-up f32->bf16
  return (short)((__float_as_uint(f) + 0x8000u) >> 16);
}
__device__ __forceinline__ float bfs2f(short s) {  // bf16->f32
  return __uint_as_float(((uint32_t)(unsigned short)s) << 16);
}
__device__ __forceinline__ short8 ld_frag(const short* p) {  // 8B-aligned 16B LDS read
  short4v a = *(const short4v*)p;
  short4v b = *(const short4v*)(p + 4);
  return __builtin_shufflevector(a, b, 0, 1, 2, 3, 4, 5, 6, 7);
}
__device__ __forceinline__ f32x4 mfma16(short8 a, short8 b, f32x4 c) {
  return __builtin_amdgcn_mfma_f32_16x16x32_bf16(a, b, c, 0, 0, 0);
}

// ---------------- Kernel 0: prep — transpose+split x -> bf16 hi/lo [b][n][c];
// convert w_qkv / w_out -> bf16 hi/lo ([o][c], k-contiguous).
__global__ __launch_bounds__(256) void prep_k(
    const float* __restrict__ x, const float* __restrict__ w_qkv,
    const float* __restrict__ w_out,
    short* __restrict__ xh, short* __restrict__ xl,
    short* __restrict__ wqh, short* __restrict__ wql,
    short* __restrict__ woh, short* __restrict__ wol) {
  const int t = threadIdx.x;
  const int bx = blockIdx.x;
  if (bx < 1024) {  // x transpose blocks: 64 n x 64 c per block
    __shared__ float T[64 * 65];  // [n][c-chunk], pitch 65 (2-way banks = free)
    const int b = bx >> 8, n0 = ((bx >> 2) & 63) * 64, c0 = (bx & 3) * 64;
    const float* xb = x + (size_t)b * C_IN * N_SP;
    {  // read 64c x 64n coalesced (wave reads 64 consecutive n at fixed c)
      const int n = t & 63, cw = t >> 6;
#pragma unroll
      for (int i = 0; i < 16; ++i) {
        const int c = cw * 16 + i;
        T[n * 65 + c] = xb[(size_t)(c0 + c) * N_SP + n0 + n];
      }
    }
    __syncthreads();
    {  // write hi/lo rows [n][c]: 16B stores, 4 lanes cover 32B/row
      const int n = t >> 2, cg = t & 3;
#pragma unroll
      for (int j = 0; j < 2; ++j) {
        const int c = cg * 16 + j * 8;
        short8 hv, lv;
#pragma unroll
        for (int e = 0; e < 8; ++e) {
          const float v = T[n * 65 + c + e];
          const short hh = f2bfs(v);
          hv[e] = hh;
          lv[e] = f2bfs(v - bfs2f(hh));
        }
        const size_t off = ((size_t)(b * N_SP + n0 + n)) * C_IN + c0 + c;
        *(short8*)(xh + off) = hv;
        *(short8*)(xl + off) = lv;
      }
    }
  } else {  // weight blocks: flat convert 131072 floats
    const int f0 = (bx - 1024) * 8192;
#pragma unroll
    for (int j = 0; j < 32; ++j) {
      const int f = f0 + j * 256 + t;
      float v;
      short *dh, *dl;
      int idx;
      if (f < 384 * 256) { v = w_qkv[f]; dh = wqh; dl = wql; idx = f; }
      else { idx = f - 384 * 256; v = w_out[idx]; dh = woh; dl = wol; }
      const short hh = f2bfs(v);
      dh[idx] = hh;
      dl[idx] = f2bfs(v - bfs2f(hh));
    }
  }
}

// ---------------- Kernel 1: QKV projection, bf16x3 MFMA (unchanged) ----------------
__global__ __launch_bounds__(256) void qkv_mfma_k(
    const short* __restrict__ xh, const short* __restrict__ xl,
    const short* __restrict__ wqh, const short* __restrict__ wql,
    short* __restrict__ qt, short* __restrict__ kt, short* __restrict__ vt) {
  const int t = threadIdx.x;
  const int lane = t & 63, w = t >> 6;
  const int l15 = lane & 15, quad = lane >> 4;
  const int osec = blockIdx.y, b = blockIdx.z;
  const int n0 = blockIdx.x * 64 + w * 16;
  const size_t xrow = ((size_t)(b * N_SP + n0 + l15)) * C_IN;
  const size_t wrow = ((size_t)(osec * 128 + l15)) * C_IN;
  const bool isv = (osec == 2);
  const f32x4 zz = {0.f, 0.f, 0.f, 0.f};
  f32x4 acc[8];
#pragma unroll
  for (int ot = 0; ot < 8; ++ot) acc[ot] = zz;

  for (int k0 = 0; k0 < C_IN; k0 += 32) {
    const int ko = k0 + quad * 8;
    const short8 xhf = *(const short8*)(xh + xrow + ko);
    const short8 xlf = *(const short8*)(xl + xrow + ko);
#pragma unroll
    for (int ot = 0; ot < 8; ++ot) {
      const size_t wo = wrow + (size_t)ot * 16 * C_IN + ko;
      const short8 whf = *(const short8*)(wqh + wo);
      const short8 wlf = *(const short8*)(wql + wo);
      if (isv) {  // A = x (rows n), B = w (rows o)
        acc[ot] = mfma16(xhf, whf, acc[ot]);
        acc[ot] = mfma16(xlf, whf, acc[ot]);
        acc[ot] = mfma16(xhf, wlf, acc[ot]);
      } else {    // A = w (rows o), B = x (rows n)
        acc[ot] = mfma16(whf, xhf, acc[ot]);
        acc[ot] = mfma16(whf, xlf, acc[ot]);
        acc[ot] = mfma16(wlf, xhf, acc[ot]);
      }
    }
  }

  if (!isv) {  // lane holds o = osec*128 + ot*16 + quad*4 + r, n = n0 + l15
    const float sc = osec ? 1.f : (0.17677669529663687f * 1.4426950408889634f);
    short* dst = osec ? kt : qt;
    const int n = n0 + l15;
#pragma unroll
    for (int ot = 0; ot < 8; ++ot) {
      const int ol = ot * 16 + quad * 4;
      const int h = ol >> 5, d0 = ol & 31;
      short4v p;
#pragma unroll
      for (int r = 0; r < 4; ++r) p[r] = f2bfs(acc[ot][r] * sc);
      *(short4v*)(dst + ((size_t)(b * HEADS + h) * N_SP + n) * DH + d0) = p;
    }
  } else {     // lane holds n = n0 + quad*4 + r, o = 256 + ot*16 + l15
    const int n = n0 + quad * 4;
#pragma unroll
    for (int ot = 0; ot < 8; ++ot) {
      const int ol = ot * 16 + l15;
      const int h = ol >> 5, d = ol & 31;
      short4v p;
#pragma unroll
      for (int r = 0; r < 4; ++r) p[r] = f2bfs(acc[ot][r]);
      *(short4v*)(vt + ((size_t)(b * HEADS + h) * DH + d) * N_SP + n) = p;
    }
  }
}

// ---------------- Kernel 2: flash attention, split-j x2, partial O/l out -------
// Round-6 changes vs round-5:
//  * Osh epilogue buffer removed -> LDS 34304->17408 B (Ps only), no __syncthreads.
//    Direct po store uses the verified mapping o_acc[tt][dt][r] =
//    O[i = w*32+tt*16+quad*4+r][d = dt*16+l15].
//  * s_setprio removed (m190: negative on lockstep structures; all waves here
//    run the same phase pattern -> prio toggling deprioritizes peers).
//  * lsum VALU adds (32/body) replaced by 4 ones-MFMA row-sums on the matrix
//    pipe; l becomes sum of bf16 P (consistent with PV numerator).
__global__ __launch_bounds__(256, 2) void attn_k(
    const short* __restrict__ qt, const short* __restrict__ kt,
    const short* __restrict__ vt, float* __restrict__ po,
    float* __restrict__ lws) {
  __shared__ short Ps[BI * PP];    // 17408 B, [i][j] bf16, rows owned per-wave
  const int t = threadIdx.x;
  const int lane = t & 63, w = t >> 6;
  const int l15 = lane & 15, quad = lane >> 4;
  const int i0 = blockIdx.x * BI;
  const int bh = blockIdx.y;
  const int part = blockIdx.z;
  const int jbase = part * JHALF;
  const short* qg = qt + ((size_t)bh * N_SP + i0) * DH;
  const short* kg = kt + ((size_t)bh * N_SP + jbase) * DH;  // part-local K
  const short* vg = vt + (size_t)bh * DH * N_SP + jbase;    // part-local V cols

  // Q fragments (loop-invariant): B[n=i][k=d]
  short8 bq[2];
#pragma unroll
  for (int tt = 0; tt < 2; ++tt)
    bq[tt] = *(const short8*)(qg + (size_t)(w * 32 + tt * 16 + l15) * DH + quad * 8);

  const f32x4 zz = {0.f, 0.f, 0.f, 0.f};
  f32x4 o_acc[2][2] = {{zz, zz}, {zz, zz}};  // [tt][dt]
  f32x4 l_acc[2] = {zz, zz};                 // row-sums via ones-MFMA
  short8 ones;
#pragma unroll
  for (int e = 0; e < 8; ++e) ones[e] = (short)0x3F80;  // bf16 1.0
  short* prow[2];
#pragma unroll
  for (int tt = 0; tt < 2; ++tt) prow[tt] = Ps + (w * 32 + tt * 16 + l15) * PP;

  short8 akA[4], akB[4], vbA[2][2], vbB[2][2];
#pragma unroll
  for (int jt = 0; jt < 4; ++jt)
    akA[jt] = *(const short8*)(kg + (size_t)(jt * 16 + l15) * DH + quad * 8);
#pragma unroll
  for (int dt = 0; dt < 2; ++dt)
#pragma unroll
    for (int kk = 0; kk < 2; ++kk)
      vbA[dt][kk] = *(const short8*)(vg + (size_t)(dt * 16 + l15) * N_SP + kk * 32 + quad * 8);

  auto body = [&](const short8 (&akc)[4], const short8 (&vbc)[2][2],
                  short8 (&akn)[4], short8 (&vbn)[2][2], int jn) {
    // S^T tiles: D[j][i] = mfma(K, Q)
    f32x4 sf[2][4];
#pragma unroll
    for (int tt = 0; tt < 2; ++tt)
#pragma unroll
      for (int jt = 0; jt < 4; ++jt) sf[tt][jt] = mfma16(akc[jt], bq[tt], zz);
    // prefetch next tile's K/V into the alternate register set
#pragma unroll
    for (int jt = 0; jt < 4; ++jt)
      akn[jt] = *(const short8*)(kg + (size_t)(jn + jt * 16 + l15) * DH + quad * 8);
#pragma unroll
    for (int dt = 0; dt < 2; ++dt)
#pragma unroll
      for (int kk = 0; kk < 2; ++kk)
        vbn[dt][kk] = *(const short8*)(vg + (size_t)(dt * 16 + l15) * N_SP + jn + kk * 32 + quad * 8);
    // exp2 (no max), pack P[i][j] via v_cvt_pk_bf16_f32
#pragma unroll
    for (int tt = 0; tt < 2; ++tt)
#pragma unroll
      for (int jt = 0; jt < 4; ++jt) {
        const float e0 = EXP2(sf[tt][jt][0]);
        const float e1 = EXP2(sf[tt][jt][1]);
        const float e2 = EXP2(sf[tt][jt][2]);
        const float e3 = EXP2(sf[tt][jt][3]);
        uint2 pk;
        asm("v_cvt_pk_bf16_f32 %0, %1, %2" : "=v"(pk.x) : "v"(e0), "v"(e1));
        asm("v_cvt_pk_bf16_f32 %0, %1, %2" : "=v"(pk.y) : "v"(e2), "v"(e3));
        *(uint2*)(prow[tt] + jt * 16 + quad * 4) = pk;
      }
    asm volatile("s_waitcnt lgkmcnt(0)" ::: "memory");  // same-wave P write->read
    // O += P V^T ; l += P . 1 (row-sum on the matrix pipe)
    short8 pa[2][2];
#pragma unroll
    for (int tt = 0; tt < 2; ++tt)
#pragma unroll
      for (int kk = 0; kk < 2; ++kk) pa[tt][kk] = ld_frag(prow[tt] + kk * 32 + quad * 8);
#pragma unroll
    for (int tt = 0; tt < 2; ++tt) {
#pragma unroll
      for (int dt = 0; dt < 2; ++dt) {
        o_acc[tt][dt] = mfma16(pa[tt][0], vbc[dt][0], o_acc[tt][dt]);
        o_acc[tt][dt] = mfma16(pa[tt][1], vbc[dt][1], o_acc[tt][dt]);
      }
      l_acc[tt] = mfma16(pa[tt][0], ones, l_acc[tt]);
      l_acc[tt] = mfma16(pa[tt][1], ones, l_acc[tt]);
    }
  };

  for (int jo = 0; jo < JHALF; jo += 2 * BJ) {
    body(akA, vbA, akB, vbB, (jo + BJ) & (JHALF - 1));
    body(akB, vbB, akA, vbA, (jo + 2 * BJ) & (JHALF - 1));
  }

  // l_acc[tt][r] = l for i = w*32 + tt*16 + quad*4 + r (same across l15)
  if (l15 == 0) {
#pragma unroll
    for (int tt = 0; tt < 2; ++tt)
#pragma unroll
      for (int r = 0; r < 4; ++r)
        lws[((size_t)(part * 16 + bh)) * N_SP + i0 + w * 32 + tt * 16 + quad * 4 + r] =
            l_acc[tt][r];
  }
  // direct store of unnormalized partial O: po[part][b][i][hid]
  // lane (quad,r) row i = w*32+tt*16+quad*4+r; 16 lanes (l15) span 64B contiguous
  {
    const int b = bh >> 2, h = bh & 3;
    float* pob = po + ((size_t)((part * B_SZ + b) * N_SP) + i0) * HID + h * 32;
#pragma unroll
    for (int tt = 0; tt < 2; ++tt)
#pragma unroll
      for (int dt = 0; dt < 2; ++dt)
#pragma unroll
        for (int r = 0; r < 4; ++r)
          pob[(size_t)(w * 32 + tt * 16 + quad * 4 + r) * HID + dt * 16 + l15] =
              o_acc[tt][dt][r];
  }
}

// ---------------- Kernel 3: combine partials + output projection, bf16x3 MFMA ----
// grid (64 ntiles, 2 osec, 4 b); wave = 16 n, 128 o. A-fragment built inline:
// a = (po0 + po1) * (1/(l0+l1)) -> bf16 hi/lo, amortized over 8 o-tiles.
__global__ __launch_bounds__(256) void out_mfma_k(
    const float* __restrict__ po, const float* __restrict__ lws,
    const short* __restrict__ woh, const short* __restrict__ wol,
    const float* __restrict__ bias, float* __restrict__ out) {
  const int t = threadIdx.x;
  const int lane = t & 63, w = t >> 6;
  const int l15 = lane & 15, quad = lane >> 4;
  const int osec = blockIdx.y, b = blockIdx.z;
  const int n0 = blockIdx.x * 64 + w * 16;
  const int n = n0 + l15;
  const size_t PSTR = (size_t)B_SZ * N_SP * HID;
  const float* arow = po + ((size_t)(b * N_SP) + n) * HID;
  const size_t wrow = ((size_t)(osec * 128 + l15)) * HID;
  const f32x4 zz = {0.f, 0.f, 0.f, 0.f};
  f32x4 acc[8];
#pragma unroll
  for (int ot = 0; ot < 8; ++ot) acc[ot] = zz;

  for (int k0 = 0; k0 < HID; k0 += 32) {
    const int ko = k0 + quad * 8;
    const int h = k0 >> 5;
    const int bh = b * HEADS + h;
    const float lv = lws[(size_t)bh * N_SP + n] + lws[(size_t)(16 + bh) * N_SP + n];
    const float linv = 1.f / lv;
    const float* pr = arow + ko;
    const float4 u0 = *(const float4*)(pr);
    const float4 u1 = *(const float4*)(pr + 4);
    const float4 v0 = *(const float4*)(pr + PSTR);
    const float4 v1 = *(const float4*)(pr + PSTR + 4);
    const float av[8] = {(u0.x + v0.x) * linv, (u0.y + v0.y) * linv,
                         (u0.z + v0.z) * linv, (u0.w + v0.w) * linv,
                         (u1.x + v1.x) * linv, (u1.y + v1.y) * linv,
                         (u1.z + v1.z) * linv, (u1.w + v1.w) * linv};
    short8 ahf, alf;
#pragma unroll
    for (int e = 0; e < 8; ++e) {
      const short hh = f2bfs(av[e]);
      ahf[e] = hh;
      alf[e] = f2bfs(av[e] - bfs2f(hh));
    }
#pragma unroll
    for (int ot = 0; ot < 8; ++ot) {
      const size_t wo = wrow + (size_t)ot * 16 * HID + ko;
      const short8 whf = *(const short8*)(woh + wo);
      const short8 wlf = *(const short8*)(wol + wo);
      acc[ot] = mfma16(ahf, whf, acc[ot]);
      acc[ot] = mfma16(alf, whf, acc[ot]);
      acc[ot] = mfma16(ahf, wlf, acc[ot]);
    }
  }
  // lane holds n = n0 + quad*4 + r, o = osec*128 + ot*16 + l15
#pragma unroll
  for (int ot = 0; ot < 8; ++ot) {
    const int o = osec * 128 + ot * 16 + l15;
    const float bv = bias[o];
    float4 v = make_float4(acc[ot][0] + bv, acc[ot][1] + bv,
                           acc[ot][2] + bv, acc[ot][3] + bv);
    *(float4*)(out + ((size_t)(b * C_IN + o)) * N_SP + n0 + quad * 4) = v;
  }
}

extern "C" void kernel_launch(void* const* d_in, const int* in_sizes, int n_in,
                              void* d_out, int out_size, void* d_ws, size_t ws_size,
                              hipStream_t stream) {
  const float* x = (const float*)d_in[0];
  const float* w_qkv = (const float*)d_in[1];
  const float* w_out = (const float*)d_in[2];
  const float* b_out = (const float*)d_in[3];
  float* out = (float*)d_out;

  // workspace layout, ~30.4 MiB total:
  short* xh = (short*)d_ws;                         // 4*4096*256 shorts = 8.39 MB
  short* xl = xh + (size_t)B_SZ * N_SP * C_IN;      // 8.39 MB
  short* wqh = xl + (size_t)B_SZ * N_SP * C_IN;     // 384*256*2B
  short* wql = wqh + 384 * C_IN;
  short* woh = wql + 384 * C_IN;                    // 256*128*2B
  short* wol = woh + C_IN * HID;
  short* qt = wol + C_IN * HID;                     // 16*4096*32 = 4 MB
  short* kt = qt + (size_t)16 * N_SP * DH;          // 4 MB
  short* vt = kt + (size_t)16 * N_SP * DH;          // 4 MB
  float* lws = (float*)(vt + (size_t)16 * N_SP * DH);  // 2*16*4096 f32 = 512 KB
  float* po = (float*)xh;  // partial O: 2*4*4096*128 f32 = 16.78 MB = xh+xl exactly

  prep_k<<<dim3(1040), 256, 0, stream>>>(x, w_qkv, w_out, xh, xl, wqh, wql, woh, wol);
  qkv_mfma_k<<<dim3(64, 3, B_SZ), 256, 0, stream>>>(xh, xl, wqh, wql, qt, kt, vt);
  attn_k<<<dim3(N_SP / BI, B_SZ * HEADS, 2), 256, 0, stream>>>(qt, kt, vt, po, lws);
  out_mfma_k<<<dim3(64, 2, B_SZ), 256, 0, stream>>>(po, lws, woh, wol, b_out, out);
}